// Round 12
// baseline (886.966 us; speedup 1.0000x reference)
//
#include <hip/hip_runtime.h>
#include <math.h>

#define HID 64
#define NSLOPE 0.2f
#define SB 512
#define EXCAP 256
#define BCAP 8192   // bucket capacity (mean 4096, 64-sigma margin; overflow -> direct path)

typedef __attribute__((ext_vector_type(8))) short short8v;
typedef __attribute__((ext_vector_type(4))) float float4v;

__device__ inline unsigned short f2bf(float x) {
  unsigned u = __float_as_uint(x);
  u += 0x7fffu + ((u >> 16) & 1u);
  return (unsigned short)(u >> 16);
}
__device__ inline float bf2f(unsigned short h) {
  return __uint_as_float(((unsigned)h) << 16);
}
__device__ inline float bflo(unsigned u) { return __uint_as_float(u << 16); }
__device__ inline float bfhi(unsigned u) { return __uint_as_float(u & 0xffff0000u); }

// ---------------- split f32 -> (hi, lo) bf16 planes, elementwise ----------------
__global__ __launch_bounds__(256) void k_split(const float* __restrict__ x,
    unsigned short* __restrict__ hi, unsigned short* __restrict__ lo, int n) {
  int i = blockIdx.x * 256 + threadIdx.x;
  if (i < n) {
    float v = x[i];
    unsigned short h = f2bf(v);
    hi[i] = h;
    lo[i] = f2bf(v - bf2f(h));
  }
}

// ---------------- W [K,N] f32 -> Wt hi/lo [N,K] bf16 ----------------
__global__ __launch_bounds__(256) void k_wsplit(const float* __restrict__ W,
    unsigned short* __restrict__ Whi, unsigned short* __restrict__ Wlo, int K, int N) {
  int i = blockIdx.x * 256 + threadIdx.x;
  if (i < N * K) {
    int n = i / K, k = i - n * K;
    float v = W[(size_t)k * N + n];
    unsigned short h = f2bf(v);
    Whi[i] = h;
    Wlo[i] = f2bf(v - bf2f(h));
  }
}

// ---------------- split-bf16 MFMA GEMM + packed-bf16 gather copy ----------------
__global__ __launch_bounds__(256) void gemm_split(
    const unsigned short* __restrict__ Ahi, const unsigned short* __restrict__ Alo,
    const unsigned short* __restrict__ Bhi, const unsigned short* __restrict__ Blo,
    float* __restrict__ C, unsigned short* __restrict__ Gp, int M, int Nc, int K, int H) {
  __shared__ __align__(16) unsigned short AsHi[128 * 40];
  __shared__ __align__(16) unsigned short AsLo[128 * 40];
  __shared__ __align__(16) unsigned short BsHi[128 * 40];
  __shared__ __align__(16) unsigned short BsLo[128 * 40];
  const int tid = threadIdx.x;
  const int lane = tid & 63, wid = tid >> 6;
  const int wr = wid >> 1, wc = wid & 1;
  const int row0 = blockIdx.y * 128;
  const int col0 = blockIdx.x * 128;
  float4v acc[4][4];
  #pragma unroll
  for (int mi = 0; mi < 4; ++mi)
    #pragma unroll
    for (int ni = 0; ni < 4; ++ni)
      acc[mi][ni] = (float4v){0.f, 0.f, 0.f, 0.f};

  const int sr = tid >> 2;
  const int sc8 = (tid & 3) * 8;
  const int lr = lane & 15, lk = (lane >> 4) * 8;

  for (int k0 = 0; k0 < K; k0 += 32) {
    #pragma unroll
    for (int half = 0; half < 2; ++half) {
      int row = sr + half * 64;
      int arow = row0 + row; if (arow > M - 1) arow = M - 1;
      int brow = col0 + row; if (brow > Nc - 1) brow = Nc - 1;
      *(short8v*)&AsHi[row * 40 + sc8] = *(const short8v*)&Ahi[(size_t)arow * K + k0 + sc8];
      *(short8v*)&AsLo[row * 40 + sc8] = *(const short8v*)&Alo[(size_t)arow * K + k0 + sc8];
      *(short8v*)&BsHi[row * 40 + sc8] = *(const short8v*)&Bhi[(size_t)brow * K + k0 + sc8];
      *(short8v*)&BsLo[row * 40 + sc8] = *(const short8v*)&Blo[(size_t)brow * K + k0 + sc8];
    }
    __syncthreads();
    short8v ah[4], alv[4], bh[4], bl[4];
    #pragma unroll
    for (int mi = 0; mi < 4; ++mi) {
      int r = wr * 64 + mi * 16 + lr;
      ah[mi]  = *(const short8v*)&AsHi[r * 40 + lk];
      alv[mi] = *(const short8v*)&AsLo[r * 40 + lk];
    }
    #pragma unroll
    for (int ni = 0; ni < 4; ++ni) {
      int r = wc * 64 + ni * 16 + lr;
      bh[ni] = *(const short8v*)&BsHi[r * 40 + lk];
      bl[ni] = *(const short8v*)&BsLo[r * 40 + lk];
    }
    #pragma unroll
    for (int mi = 0; mi < 4; ++mi)
      #pragma unroll
      for (int ni = 0; ni < 4; ++ni) {
        acc[mi][ni] = __builtin_amdgcn_mfma_f32_16x16x32_bf16(ah[mi], bh[ni], acc[mi][ni], 0, 0, 0);
        acc[mi][ni] = __builtin_amdgcn_mfma_f32_16x16x32_bf16(ah[mi], bl[ni], acc[mi][ni], 0, 0, 0);
        acc[mi][ni] = __builtin_amdgcn_mfma_f32_16x16x32_bf16(alv[mi], bh[ni], acc[mi][ni], 0, 0, 0);
      }
    __syncthreads();
  }
  #pragma unroll
  for (int mi = 0; mi < 4; ++mi) {
    int rbase = row0 + wr * 64 + mi * 16 + (lane >> 4) * 4;
    #pragma unroll
    for (int ni = 0; ni < 4; ++ni) {
      int cc = col0 + wc * 64 + ni * 16 + (lane & 15);
      if (cc < Nc) {
        int gcol = (cc & 63) * H + (cc >> 6);
        #pragma unroll
        for (int q = 0; q < 4; ++q) {
          int rr = rbase + q;
          if (rr < M) {
            float v = acc[mi][ni][q];
            C[(size_t)rr * Nc + cc] = v;
            Gp[(size_t)rr * Nc + gcol] = f2bf(v);
          }
        }
      }
    }
  }
}

// ---------------- per-node attention logits el/er (4 nodes / 256-thread block) ----
__global__ __launch_bounds__(256) void elr_kernel(const float* __restrict__ h,
    const float* __restrict__ al, const float* __restrict__ ar,
    float* __restrict__ el, float* __restrict__ er, int H, int N) {
  int n = blockIdx.x * 4 + (threadIdx.x >> 6);
  int lane = threadIdx.x & 63;
  if (n >= N) return;
  const float* hr = h + (size_t)n * H * HID;
  for (int hh = 0; hh < H; ++hh) {
    float v = hr[hh * HID + lane];
    float a = v * al[hh * HID + lane];
    float b = v * ar[hh * HID + lane];
    #pragma unroll
    for (int o = 32; o > 0; o >>= 1) { a += __shfl_xor(a, o); b += __shfl_xor(b, o); }
    if (lane == 0) { el[n * H + hh] = a; er[n * H + hh] = b; }
  }
}

// ---------------- CSR build ----------------
__global__ void k_count(const int* __restrict__ dst, int* __restrict__ deg, int E) {
  int e = blockIdx.x * blockDim.x + threadIdx.x;
  if (e < E) atomicAdd(&deg[dst[e]], 1);
}
__global__ __launch_bounds__(SB) void k_blocksums(const int* __restrict__ deg,
                                                  int* __restrict__ bsums, int n) {
  __shared__ int s[SB];
  int t = threadIdx.x, i = blockIdx.x * SB + t;
  s[t] = (i < n) ? deg[i] : 0;
  __syncthreads();
  for (int o = SB >> 1; o > 0; o >>= 1) { if (t < o) s[t] += s[t + o]; __syncthreads(); }
  if (t == 0) bsums[blockIdx.x] = s[0];
}
__global__ __launch_bounds__(SB) void k_scancarry(const int* __restrict__ bsums,
                                                   int* __restrict__ carry, int nb) {
  __shared__ int s[SB];
  int t = threadIdx.x;
  int v = (t < nb) ? bsums[t] : 0;
  s[t] = v; __syncthreads();
  for (int o = 1; o < SB; o <<= 1) {
    int u = (t >= o) ? s[t - o] : 0;
    __syncthreads(); s[t] += u; __syncthreads();
  }
  if (t < nb) carry[t] = s[t] - v;
}
__global__ __launch_bounds__(SB) void k_offsets(const int* __restrict__ deg,
    const int* __restrict__ carry, int* __restrict__ offs, int n, int E) {
  __shared__ int s[SB];
  int t = threadIdx.x, i = blockIdx.x * SB + t;
  int v = (i < n) ? deg[i] : 0;
  s[t] = v; __syncthreads();
  for (int o = 1; o < SB; o <<= 1) {
    int u = (t >= o) ? s[t - o] : 0;
    __syncthreads(); s[t] += u; __syncthreads();
  }
  if (i < n) offs[i] = carry[blockIdx.x] + s[t] - v;
  if (i == n) offs[n] = E;
}
// pass A: bin edges by dst>>8 (N<65536 -> edge packs into one u32). Concentrated
// per-bucket write regions keep line amplification low. Overflow -> direct scatter.
__global__ void k_binA(const int* __restrict__ src, const int* __restrict__ dst,
                       int* __restrict__ bcur, unsigned* __restrict__ bbuf,
                       const int* __restrict__ offs, int* __restrict__ cursor,
                       int* __restrict__ esrc, int E) {
  int e = blockIdx.x * 256 + threadIdx.x;
  if (e >= E) return;
  int d = dst[e], s = src[e];
  int b = d >> 8;
  int pos = atomicAdd(&bcur[b], 1);
  if (pos < BCAP) {
    bbuf[(size_t)b * BCAP + pos] = ((unsigned)d << 16) | (unsigned)s;
  } else {
    int slot = offs[d] + atomicAdd(&cursor[d], 1);
    esrc[slot] = s;
  }
}
// pass B: one block per bucket; scatter within the bucket's ~16KB slot window.
__global__ __launch_bounds__(256) void k_binB(const int* __restrict__ bcur,
    const unsigned* __restrict__ bbuf, const int* __restrict__ offs,
    int* __restrict__ cursor, int* __restrict__ esrc) {
  int b = blockIdx.x;
  int cnt = bcur[b]; if (cnt > BCAP) cnt = BCAP;
  for (int i = threadIdx.x; i < cnt; i += 256) {
    unsigned v = bbuf[(size_t)b * BCAP + i];
    int d = (int)(v >> 16), s = (int)(v & 0xffffu);
    int slot = offs[d] + atomicAdd(&cursor[d], 1);
    esrc[slot] = s;
  }
}

// ---- fused per-dst softmax + weighted gather-sum (r8-best structure).
// H=4: 32 lanes/node (2 nodes/wave); H=1: 16 lanes/node (4 nodes/wave).
template<int H, bool DO_ELU, bool SPLITOUT>
__global__ __launch_bounds__(64) void agg_kernel(const unsigned short* __restrict__ gp,
    const float* __restrict__ el, const float* __restrict__ er,
    const int* __restrict__ offs, const int* __restrict__ esrc,
    const float* __restrict__ bias,
    unsigned short* __restrict__ outHi, unsigned short* __restrict__ outLo,
    float* __restrict__ outF, int N) {
  constexpr int LPN = (H == 4) ? 32 : 16;
  constexpr int NPW = 64 / LPN;
  __shared__ __align__(16) float exs_all[NPW][EXCAP * H];
  const int lane = threadIdx.x;
  const int grp = lane / LPN;
  const int sl = lane % LPN;
  const int n = blockIdx.x * NPW + grp;
  if (n >= N) return;
  float* exs = exs_all[grp];
  const int off = offs[n];
  const int deg = offs[n + 1] - off;
  float ern[H];
  if (H == 4) {
    float4 R = *(const float4*)&er[n * 4];
    ern[0] = R.x; ern[1] = R.y; ern[2] = R.z; ern[3] = R.w;
  } else {
    ern[0] = er[n];
  }
  float sum[H];
  #pragma unroll
  for (int h = 0; h < H; ++h) sum[h] = 0.f;
  for (int base = 0; base < deg; base += LPN) {
    int i = base + sl;
    if (i < deg) {
      int s = esrc[off + i];
      if (H == 4) {
        float4 L = *(const float4*)&el[s * 4];
        float lv[4] = {L.x, L.y, L.z, L.w};
        float exv[4];
        #pragma unroll
        for (int h = 0; h < 4; ++h) {
          float e = lv[h] + ern[h];
          e = e > 0.f ? e : NSLOPE * e;
          exv[h] = __expf(fminf(e, 80.f));
          sum[h] += exv[h];
        }
        if (i < EXCAP)
          *(float4*)&exs[i * 4] = make_float4(exv[0], exv[1], exv[2], exv[3]);
      } else {
        float e = el[s] + ern[0];
        e = e > 0.f ? e : NSLOPE * e;
        float x = __expf(fminf(e, 80.f));
        sum[0] += x;
        if (i < EXCAP) exs[i] = x;
      }
    }
  }
  float inv[H];
  #pragma unroll
  for (int h = 0; h < H; ++h) {
    float v = sum[h];
    #pragma unroll
    for (int o = LPN / 2; o > 0; o >>= 1) v += __shfl_xor(v, o);
    inv[h] = v > 0.f ? 1.f / v : 0.f;
  }
  asm volatile("s_waitcnt lgkmcnt(0)" ::: "memory");
  const int degc = deg < EXCAP ? deg : EXCAP;
  int t = 0;
  if (H == 4) {
    float acc[8];
    #pragma unroll
    for (int k = 0; k < 8; ++k) acc[k] = 0.f;
    for (; t + 4 <= degc; t += 4) {
      int4 sa = *(const int4*)&esrc[off + t];
      int s[4] = {sa.x, sa.y, sa.z, sa.w};
      uint4 g[4];
      #pragma unroll
      for (int j = 0; j < 4; ++j)
        g[j] = *(const uint4*)&gp[(size_t)s[j] * 256 + sl * 8];
      #pragma unroll
      for (int j = 0; j < 4; ++j) {
        float4 x = *(const float4*)&exs[(t + j) * 4];
        acc[0] = fmaf(bflo(g[j].x), x.x, acc[0]);
        acc[1] = fmaf(bfhi(g[j].x), x.y, acc[1]);
        acc[2] = fmaf(bflo(g[j].y), x.z, acc[2]);
        acc[3] = fmaf(bfhi(g[j].y), x.w, acc[3]);
        acc[4] = fmaf(bflo(g[j].z), x.x, acc[4]);
        acc[5] = fmaf(bfhi(g[j].z), x.y, acc[5]);
        acc[6] = fmaf(bflo(g[j].w), x.z, acc[6]);
        acc[7] = fmaf(bfhi(g[j].w), x.w, acc[7]);
      }
    }
    for (; t < degc; ++t) {
      int s = esrc[off + t];
      uint4 g = *(const uint4*)&gp[(size_t)s * 256 + sl * 8];
      float4 x = *(const float4*)&exs[t * 4];
      acc[0] = fmaf(bflo(g.x), x.x, acc[0]);
      acc[1] = fmaf(bfhi(g.x), x.y, acc[1]);
      acc[2] = fmaf(bflo(g.y), x.z, acc[2]);
      acc[3] = fmaf(bfhi(g.y), x.w, acc[3]);
      acc[4] = fmaf(bflo(g.z), x.x, acc[4]);
      acc[5] = fmaf(bfhi(g.z), x.y, acc[5]);
      acc[6] = fmaf(bflo(g.w), x.z, acc[6]);
      acc[7] = fmaf(bfhi(g.w), x.w, acc[7]);
    }
    for (; t < deg; ++t) {
      int s = esrc[off + t];
      float4 L = *(const float4*)&el[s * 4];
      float lv[4] = {L.x, L.y, L.z, L.w};
      float xv[4];
      #pragma unroll
      for (int h = 0; h < 4; ++h) {
        float e = lv[h] + ern[h];
        e = e > 0.f ? e : NSLOPE * e;
        xv[h] = __expf(fminf(e, 80.f));
      }
      uint4 g = *(const uint4*)&gp[(size_t)s * 256 + sl * 8];
      acc[0] = fmaf(bflo(g.x), xv[0], acc[0]);
      acc[1] = fmaf(bfhi(g.x), xv[1], acc[1]);
      acc[2] = fmaf(bflo(g.y), xv[2], acc[2]);
      acc[3] = fmaf(bfhi(g.y), xv[3], acc[3]);
      acc[4] = fmaf(bflo(g.z), xv[0], acc[4]);
      acc[5] = fmaf(bfhi(g.z), xv[1], acc[5]);
      acc[6] = fmaf(bflo(g.w), xv[2], acc[6]);
      acc[7] = fmaf(bfhi(g.w), xv[3], acc[7]);
    }
    #pragma unroll
    for (int dd = 0; dd < 2; ++dd) {
      int d = 2 * sl + dd;
      #pragma unroll
      for (int hh = 0; hh < 4; ++hh) {
        float v = fmaf(acc[dd * 4 + hh], inv[hh], bias[hh * HID + d]);
        if (DO_ELU) v = v > 0.f ? v : expm1f(v);
        size_t oi = (size_t)n * 256 + hh * HID + d;
        if (SPLITOUT) {
          unsigned short hb = f2bf(v);
          outHi[oi] = hb;
          outLo[oi] = f2bf(v - bf2f(hb));
        } else {
          outF[oi] = v;
        }
      }
    }
  } else {
    float acc[4];
    #pragma unroll
    for (int k = 0; k < 4; ++k) acc[k] = 0.f;
    for (; t + 8 <= degc; t += 8) {
      int4 sa = *(const int4*)&esrc[off + t];
      int4 sb = *(const int4*)&esrc[off + t + 4];
      int s[8] = {sa.x, sa.y, sa.z, sa.w, sb.x, sb.y, sb.z, sb.w};
      uint2 g[8];
      #pragma unroll
      for (int j = 0; j < 8; ++j)
        g[j] = *(const uint2*)&gp[(size_t)s[j] * 64 + sl * 4];
      #pragma unroll
      for (int j = 0; j < 8; ++j) {
        float x = exs[t + j];
        acc[0] = fmaf(bflo(g[j].x), x, acc[0]);
        acc[1] = fmaf(bfhi(g[j].x), x, acc[1]);
        acc[2] = fmaf(bflo(g[j].y), x, acc[2]);
        acc[3] = fmaf(bfhi(g[j].y), x, acc[3]);
      }
    }
    for (; t < degc; ++t) {
      int s = esrc[off + t];
      uint2 g = *(const uint2*)&gp[(size_t)s * 64 + sl * 4];
      float x = exs[t];
      acc[0] = fmaf(bflo(g.x), x, acc[0]);
      acc[1] = fmaf(bfhi(g.x), x, acc[1]);
      acc[2] = fmaf(bflo(g.y), x, acc[2]);
      acc[3] = fmaf(bfhi(g.y), x, acc[3]);
    }
    for (; t < deg; ++t) {
      int s = esrc[off + t];
      float e = el[s] + ern[0];
      e = e > 0.f ? e : NSLOPE * e;
      float x = __expf(fminf(e, 80.f));
      uint2 g = *(const uint2*)&gp[(size_t)s * 64 + sl * 4];
      acc[0] = fmaf(bflo(g.x), x, acc[0]);
      acc[1] = fmaf(bfhi(g.x), x, acc[1]);
      acc[2] = fmaf(bflo(g.y), x, acc[2]);
      acc[3] = fmaf(bfhi(g.y), x, acc[3]);
    }
    #pragma unroll
    for (int k = 0; k < 4; ++k) {
      int d = 4 * sl + k;
      float v = fmaf(acc[k], inv[0], bias[d]);
      if (DO_ELU) v = v > 0.f ? v : expm1f(v);
      size_t oi = (size_t)n * HID + d;
      if (SPLITOUT) {
        unsigned short hb = f2bf(v);
        outHi[oi] = hb;
        outLo[oi] = f2bf(v - bf2f(hb));
      } else {
        outF[oi] = v;
      }
    }
  }
}

extern "C" void kernel_launch(void* const* d_in, const int* in_sizes, int n_in,
                              void* d_out, int out_size, void* d_ws, size_t ws_size,
                              hipStream_t stream) {
  const float* feat = (const float*)d_in[0];
  const int* src = (const int*)d_in[1];
  const int* dst = (const int*)d_in[2];
  const float* W1 = (const float*)d_in[3];
  const float* al1 = (const float*)d_in[4];
  const float* ar1 = (const float*)d_in[5];
  const float* b1 = (const float*)d_in[6];
  const float* W2 = (const float*)d_in[7];
  const float* al2 = (const float*)d_in[8];
  const float* ar2 = (const float*)d_in[9];
  const float* b2 = (const float*)d_in[10];
  const float* W3 = (const float*)d_in[11];
  const float* al3 = (const float*)d_in[12];
  const float* ar3 = (const float*)d_in[13];
  const float* b3 = (const float*)d_in[14];
  const int N = in_sizes[0] / 128;  // 50000 (< 65536 required for u32 edge packing)
  const int E = in_sizes[1];        // 800000

  char* w = (char*)d_ws;
  auto alloc = [&](size_t bytes) {
    void* p = (void*)w;
    w += (bytes + 255) & ~(size_t)255;
    return p;
  };
  unsigned short* pHi = (unsigned short*)alloc((size_t)N * 256 * 2);
  unsigned short* pLo = (unsigned short*)alloc((size_t)N * 256 * 2);
  float* Cbuf = (float*)alloc((size_t)N * 256 * 4);
  unsigned short* Gp = (unsigned short*)alloc((size_t)N * 256 * 2);
  float* el = (float*)alloc((size_t)N * 4 * 4);
  float* er = (float*)alloc((size_t)N * 4 * 4);
  int* deg = (int*)alloc((size_t)N * 4);
  int* cursor = (int*)alloc((size_t)N * 4);
  int* offs = (int*)alloc((size_t)(N + 1) * 4);
  int nb = (N + SB - 1) / SB;
  int* bsums = (int*)alloc((size_t)nb * 4);
  int* carry = (int*)alloc((size_t)nb * 4);
  int* esrc = (int*)alloc((size_t)E * 4);
  int nbk = (N + 255) >> 8;  // 196 buckets
  int* bcur = (int*)alloc((size_t)nbk * 4);
  unsigned* bbuf = (unsigned*)alloc((size_t)nbk * BCAP * 4);
  unsigned short* W1h = (unsigned short*)alloc((size_t)256 * 128 * 2);
  unsigned short* W1l = (unsigned short*)alloc((size_t)256 * 128 * 2);
  unsigned short* W2h = (unsigned short*)alloc((size_t)256 * 256 * 2);
  unsigned short* W2l = (unsigned short*)alloc((size_t)256 * 256 * 2);
  unsigned short* W3h = (unsigned short*)alloc((size_t)64 * 256 * 2);
  unsigned short* W3l = (unsigned short*)alloc((size_t)64 * 256 * 2);

  // ---- CSR by dst (binned two-pass fill) ----
  hipMemsetAsync(deg, 0, (size_t)N * 4, stream);
  hipMemsetAsync(cursor, 0, (size_t)N * 4, stream);
  hipMemsetAsync(bcur, 0, (size_t)nbk * 4, stream);
  int eb = (E + 255) / 256;
  k_count<<<eb, 256, 0, stream>>>(dst, deg, E);
  k_blocksums<<<nb, SB, 0, stream>>>(deg, bsums, N);
  k_scancarry<<<1, SB, 0, stream>>>(bsums, carry, nb);
  k_offsets<<<nb, SB, 0, stream>>>(deg, carry, offs, N, E);
  k_binA<<<eb, 256, 0, stream>>>(src, dst, bcur, bbuf, offs, cursor, esrc, E);
  k_binB<<<nbk, 256, 0, stream>>>(bcur, bbuf, offs, cursor, esrc);

  // ---- weight transpose+split ----
  k_wsplit<<<(256 * 128 + 255) / 256, 256, 0, stream>>>(W1, W1h, W1l, 128, 256);
  k_wsplit<<<(256 * 256 + 255) / 256, 256, 0, stream>>>(W2, W2h, W2l, 256, 256);
  k_wsplit<<<(64 * 256 + 255) / 256, 256, 0, stream>>>(W3, W3h, W3l, 256, 64);

  // ---- feat split ----
  k_split<<<((N * 128) + 255) / 256, 256, 0, stream>>>(feat, pHi, pLo, N * 128);

  int rg = (N + 127) / 128;   // 391
  int ng4 = (N + 3) / 4;      // elr blocks
  int ag4 = (N + 1) / 2;      // agg<4>: 2 nodes/wave
  int ag1 = (N + 3) / 4;      // agg<1>: 4 nodes/wave
  // ---- layer 1 ----
  gemm_split<<<dim3(2, rg), 256, 0, stream>>>(pHi, pLo, W1h, W1l, Cbuf, Gp, N, 256, 128, 4);
  elr_kernel<<<ng4, 256, 0, stream>>>(Cbuf, al1, ar1, el, er, 4, N);
  agg_kernel<4, true, true><<<ag4, 64, 0, stream>>>(Gp, el, er, offs, esrc, b1, pHi, pLo, nullptr, N);
  // ---- layer 2 ----
  gemm_split<<<dim3(2, rg), 256, 0, stream>>>(pHi, pLo, W2h, W2l, Cbuf, Gp, N, 256, 256, 4);
  elr_kernel<<<ng4, 256, 0, stream>>>(Cbuf, al2, ar2, el, er, 4, N);
  agg_kernel<4, true, true><<<ag4, 64, 0, stream>>>(Gp, el, er, offs, esrc, b2, pHi, pLo, nullptr, N);
  // ---- layer 3 ----
  gemm_split<<<dim3(1, rg), 256, 0, stream>>>(pHi, pLo, W3h, W3l, Cbuf, Gp, N, 64, 256, 1);
  elr_kernel<<<ng4, 256, 0, stream>>>(Cbuf, al3, ar3, el, er, 1, N);
  agg_kernel<1, false, false><<<ag1, 64, 0, stream>>>(Gp, el, er, offs, esrc, b3, nullptr, nullptr, (float*)d_out, N);
}

// Round 13
// 443.440 us; speedup vs baseline: 2.0002x; 2.0002x over previous
//
#include <hip/hip_runtime.h>
#include <math.h>

#define HID 64
#define NSLOPE 0.2f
#define SB 512
#define EXCAP 256
#define BCAP 8192      // bucket capacity (mean 4096, +64 sigma)
#define OVFCAP 65536   // overflow list capacity (expected use: 0)
#define NBK_MAX 256    // max buckets (N < 65536)

typedef __attribute__((ext_vector_type(8))) short short8v;
typedef __attribute__((ext_vector_type(4))) float float4v;

__device__ inline unsigned short f2bf(float x) {
  unsigned u = __float_as_uint(x);
  u += 0x7fffu + ((u >> 16) & 1u);
  return (unsigned short)(u >> 16);
}
__device__ inline float bf2f(unsigned short h) {
  return __uint_as_float(((unsigned)h) << 16);
}
__device__ inline float bflo(unsigned u) { return __uint_as_float(u << 16); }
__device__ inline float bfhi(unsigned u) { return __uint_as_float(u & 0xffff0000u); }

// ---------------- split f32 -> (hi, lo) bf16 planes, elementwise ----------------
__global__ __launch_bounds__(256) void k_split(const float* __restrict__ x,
    unsigned short* __restrict__ hi, unsigned short* __restrict__ lo, int n) {
  int i = blockIdx.x * 256 + threadIdx.x;
  if (i < n) {
    float v = x[i];
    unsigned short h = f2bf(v);
    hi[i] = h;
    lo[i] = f2bf(v - bf2f(h));
  }
}

// ---------------- W [K,N] f32 -> Wt hi/lo [N,K] bf16 ----------------
__global__ __launch_bounds__(256) void k_wsplit(const float* __restrict__ W,
    unsigned short* __restrict__ Whi, unsigned short* __restrict__ Wlo, int K, int N) {
  int i = blockIdx.x * 256 + threadIdx.x;
  if (i < N * K) {
    int n = i / K, k = i - n * K;
    float v = W[(size_t)k * N + n];
    unsigned short h = f2bf(v);
    Whi[i] = h;
    Wlo[i] = f2bf(v - bf2f(h));
  }
}

// ---------------- split-bf16 MFMA GEMM + packed-bf16 gather copy ----------------
__global__ __launch_bounds__(256) void gemm_split(
    const unsigned short* __restrict__ Ahi, const unsigned short* __restrict__ Alo,
    const unsigned short* __restrict__ Bhi, const unsigned short* __restrict__ Blo,
    float* __restrict__ C, unsigned short* __restrict__ Gp, int M, int Nc, int K, int H) {
  __shared__ __align__(16) unsigned short AsHi[128 * 40];
  __shared__ __align__(16) unsigned short AsLo[128 * 40];
  __shared__ __align__(16) unsigned short BsHi[128 * 40];
  __shared__ __align__(16) unsigned short BsLo[128 * 40];
  const int tid = threadIdx.x;
  const int lane = tid & 63, wid = tid >> 6;
  const int wr = wid >> 1, wc = wid & 1;
  const int row0 = blockIdx.y * 128;
  const int col0 = blockIdx.x * 128;
  float4v acc[4][4];
  #pragma unroll
  for (int mi = 0; mi < 4; ++mi)
    #pragma unroll
    for (int ni = 0; ni < 4; ++ni)
      acc[mi][ni] = (float4v){0.f, 0.f, 0.f, 0.f};

  const int sr = tid >> 2;
  const int sc8 = (tid & 3) * 8;
  const int lr = lane & 15, lk = (lane >> 4) * 8;

  for (int k0 = 0; k0 < K; k0 += 32) {
    #pragma unroll
    for (int half = 0; half < 2; ++half) {
      int row = sr + half * 64;
      int arow = row0 + row; if (arow > M - 1) arow = M - 1;
      int brow = col0 + row; if (brow > Nc - 1) brow = Nc - 1;
      *(short8v*)&AsHi[row * 40 + sc8] = *(const short8v*)&Ahi[(size_t)arow * K + k0 + sc8];
      *(short8v*)&AsLo[row * 40 + sc8] = *(const short8v*)&Alo[(size_t)arow * K + k0 + sc8];
      *(short8v*)&BsHi[row * 40 + sc8] = *(const short8v*)&Bhi[(size_t)brow * K + k0 + sc8];
      *(short8v*)&BsLo[row * 40 + sc8] = *(const short8v*)&Blo[(size_t)brow * K + k0 + sc8];
    }
    __syncthreads();
    short8v ah[4], alv[4], bh[4], bl[4];
    #pragma unroll
    for (int mi = 0; mi < 4; ++mi) {
      int r = wr * 64 + mi * 16 + lr;
      ah[mi]  = *(const short8v*)&AsHi[r * 40 + lk];
      alv[mi] = *(const short8v*)&AsLo[r * 40 + lk];
    }
    #pragma unroll
    for (int ni = 0; ni < 4; ++ni) {
      int r = wc * 64 + ni * 16 + lr;
      bh[ni] = *(const short8v*)&BsHi[r * 40 + lk];
      bl[ni] = *(const short8v*)&BsLo[r * 40 + lk];
    }
    #pragma unroll
    for (int mi = 0; mi < 4; ++mi)
      #pragma unroll
      for (int ni = 0; ni < 4; ++ni) {
        acc[mi][ni] = __builtin_amdgcn_mfma_f32_16x16x32_bf16(ah[mi], bh[ni], acc[mi][ni], 0, 0, 0);
        acc[mi][ni] = __builtin_amdgcn_mfma_f32_16x16x32_bf16(ah[mi], bl[ni], acc[mi][ni], 0, 0, 0);
        acc[mi][ni] = __builtin_amdgcn_mfma_f32_16x16x32_bf16(alv[mi], bh[ni], acc[mi][ni], 0, 0, 0);
      }
    __syncthreads();
  }
  #pragma unroll
  for (int mi = 0; mi < 4; ++mi) {
    int rbase = row0 + wr * 64 + mi * 16 + (lane >> 4) * 4;
    #pragma unroll
    for (int ni = 0; ni < 4; ++ni) {
      int cc = col0 + wc * 64 + ni * 16 + (lane & 15);
      if (cc < Nc) {
        int gcol = (cc & 63) * H + (cc >> 6);
        #pragma unroll
        for (int q = 0; q < 4; ++q) {
          int rr = rbase + q;
          if (rr < M) {
            float v = acc[mi][ni][q];
            C[(size_t)rr * Nc + cc] = v;
            Gp[(size_t)rr * Nc + gcol] = f2bf(v);
          }
        }
      }
    }
  }
}

// ---------------- per-node attention logits el/er (4 nodes / 256-thread block) ----
__global__ __launch_bounds__(256) void elr_kernel(const float* __restrict__ h,
    const float* __restrict__ al, const float* __restrict__ ar,
    float* __restrict__ el, float* __restrict__ er, int H, int N) {
  int n = blockIdx.x * 4 + (threadIdx.x >> 6);
  int lane = threadIdx.x & 63;
  if (n >= N) return;
  const float* hr = h + (size_t)n * H * HID;
  for (int hh = 0; hh < H; ++hh) {
    float v = hr[hh * HID + lane];
    float a = v * al[hh * HID + lane];
    float b = v * ar[hh * HID + lane];
    #pragma unroll
    for (int o = 32; o > 0; o >>= 1) { a += __shfl_xor(a, o); b += __shfl_xor(b, o); }
    if (lane == 0) { el[n * H + hh] = a; er[n * H + hh] = b; }
  }
}

// ---------------- CSR build ----------------
__global__ void k_count(const int* __restrict__ dst, int* __restrict__ deg, int E) {
  int e = blockIdx.x * blockDim.x + threadIdx.x;
  if (e < E) atomicAdd(&deg[dst[e]], 1);
}
__global__ __launch_bounds__(SB) void k_blocksums(const int* __restrict__ deg,
                                                  int* __restrict__ bsums, int n) {
  __shared__ int s[SB];
  int t = threadIdx.x, i = blockIdx.x * SB + t;
  s[t] = (i < n) ? deg[i] : 0;
  __syncthreads();
  for (int o = SB >> 1; o > 0; o >>= 1) { if (t < o) s[t] += s[t + o]; __syncthreads(); }
  if (t == 0) bsums[blockIdx.x] = s[0];
}
__global__ __launch_bounds__(SB) void k_scancarry(const int* __restrict__ bsums,
                                                   int* __restrict__ carry, int nb) {
  __shared__ int s[SB];
  int t = threadIdx.x;
  int v = (t < nb) ? bsums[t] : 0;
  s[t] = v; __syncthreads();
  for (int o = 1; o < SB; o <<= 1) {
    int u = (t >= o) ? s[t - o] : 0;
    __syncthreads(); s[t] += u; __syncthreads();
  }
  if (t < nb) carry[t] = s[t] - v;
}
__global__ __launch_bounds__(SB) void k_offsets(const int* __restrict__ deg,
    const int* __restrict__ carry, int* __restrict__ offs, int n, int E) {
  __shared__ int s[SB];
  int t = threadIdx.x, i = blockIdx.x * SB + t;
  int v = (i < n) ? deg[i] : 0;
  s[t] = v; __syncthreads();
  for (int o = 1; o < SB; o <<= 1) {
    int u = (t >= o) ? s[t - o] : 0;
    __syncthreads(); s[t] += u; __syncthreads();
  }
  if (i < n) offs[i] = carry[blockIdx.x] + s[t] - v;
  if (i == n) offs[n] = E;
}
// pass A v2: LDS-aggregated bucket reservation (1 global atomic per block*bucket,
// not per edge). 256 blocks, grid-strided; pass1 count in LDS, reserve, pass2 write.
__global__ __launch_bounds__(256) void k_binA(const int* __restrict__ src,
    const int* __restrict__ dst, int* __restrict__ bcur, unsigned* __restrict__ bbuf,
    unsigned* __restrict__ ovf, int* __restrict__ ovfcnt, int E, int nbk) {
  __shared__ int lcnt[NBK_MAX];
  __shared__ int lbase[NBK_MAX];
  const int tid = threadIdx.x;
  int per = (E + gridDim.x - 1) / gridDim.x;
  int e0 = blockIdx.x * per;
  int e1 = e0 + per; if (e1 > E) e1 = E;
  for (int b = tid; b < nbk; b += 256) lcnt[b] = 0;
  __syncthreads();
  for (int e = e0 + tid; e < e1; e += 256)
    atomicAdd(&lcnt[dst[e] >> 8], 1);
  __syncthreads();
  for (int b = tid; b < nbk; b += 256) {
    int c = lcnt[b];
    lbase[b] = (c > 0) ? atomicAdd(&bcur[b], c) : 0;
    lcnt[b] = 0;
  }
  __syncthreads();
  for (int e = e0 + tid; e < e1; e += 256) {
    int d = dst[e], s = src[e];
    int b = d >> 8;
    int pos = lbase[b] + atomicAdd(&lcnt[b], 1);
    unsigned packed = ((unsigned)d << 16) | (unsigned)s;
    if (pos < BCAP) {
      bbuf[(size_t)b * BCAP + pos] = packed;
    } else {
      int o = atomicAdd(ovfcnt, 1);
      if (o < OVFCAP) ovf[o] = packed;
    }
  }
}
// pass B v2: one block per bucket; per-node cursors in LDS (bucket = 256 nodes);
// scatter within the bucket's esrc window; export cursors for the overflow pass.
__global__ __launch_bounds__(256) void k_binB(const int* __restrict__ bcur,
    const unsigned* __restrict__ bbuf, const int* __restrict__ offs,
    int* __restrict__ cursor, int* __restrict__ esrc, int N) {
  __shared__ int lcur[256];
  int b = blockIdx.x;
  int n0 = b << 8;
  int nn = N - n0; if (nn > 256) nn = 256;
  for (int i = threadIdx.x; i < 256; i += 256) lcur[i] = 0;
  __syncthreads();
  int cnt = bcur[b]; if (cnt > BCAP) cnt = BCAP;
  for (int i = threadIdx.x; i < cnt; i += 256) {
    unsigned v = bbuf[(size_t)b * BCAP + i];
    int d = (int)(v >> 16), s = (int)(v & 0xffffu);
    int slot = offs[d] + atomicAdd(&lcur[d & 255], 1);
    esrc[slot] = s;
  }
  __syncthreads();
  for (int i = threadIdx.x; i < nn; i += 256) cursor[n0 + i] = lcur[i];
}
// overflow pass: tiny (expected 0 edges); uses cursors exported by k_binB.
__global__ __launch_bounds__(64) void k_ovf(const unsigned* __restrict__ ovf,
    const int* __restrict__ ovfcnt, const int* __restrict__ offs,
    int* __restrict__ cursor, int* __restrict__ esrc) {
  int cnt = *ovfcnt; if (cnt > OVFCAP) cnt = OVFCAP;
  for (int i = threadIdx.x; i < cnt; i += 64) {
    unsigned v = ovf[i];
    int d = (int)(v >> 16), s = (int)(v & 0xffffu);
    int slot = offs[d] + atomicAdd(&cursor[d], 1);
    esrc[slot] = s;
  }
}

// ---- fused per-dst softmax + weighted gather-sum (r8-best structure).
// H=4: 32 lanes/node (2 nodes/wave); H=1: 16 lanes/node (4 nodes/wave).
template<int H, bool DO_ELU, bool SPLITOUT>
__global__ __launch_bounds__(64) void agg_kernel(const unsigned short* __restrict__ gp,
    const float* __restrict__ el, const float* __restrict__ er,
    const int* __restrict__ offs, const int* __restrict__ esrc,
    const float* __restrict__ bias,
    unsigned short* __restrict__ outHi, unsigned short* __restrict__ outLo,
    float* __restrict__ outF, int N) {
  constexpr int LPN = (H == 4) ? 32 : 16;
  constexpr int NPW = 64 / LPN;
  __shared__ __align__(16) float exs_all[NPW][EXCAP * H];
  const int lane = threadIdx.x;
  const int grp = lane / LPN;
  const int sl = lane % LPN;
  const int n = blockIdx.x * NPW + grp;
  if (n >= N) return;
  float* exs = exs_all[grp];
  const int off = offs[n];
  const int deg = offs[n + 1] - off;
  float ern[H];
  if (H == 4) {
    float4 R = *(const float4*)&er[n * 4];
    ern[0] = R.x; ern[1] = R.y; ern[2] = R.z; ern[3] = R.w;
  } else {
    ern[0] = er[n];
  }
  float sum[H];
  #pragma unroll
  for (int h = 0; h < H; ++h) sum[h] = 0.f;
  for (int base = 0; base < deg; base += LPN) {
    int i = base + sl;
    if (i < deg) {
      int s = esrc[off + i];
      if (H == 4) {
        float4 L = *(const float4*)&el[s * 4];
        float lv[4] = {L.x, L.y, L.z, L.w};
        float exv[4];
        #pragma unroll
        for (int h = 0; h < 4; ++h) {
          float e = lv[h] + ern[h];
          e = e > 0.f ? e : NSLOPE * e;
          exv[h] = __expf(fminf(e, 80.f));
          sum[h] += exv[h];
        }
        if (i < EXCAP)
          *(float4*)&exs[i * 4] = make_float4(exv[0], exv[1], exv[2], exv[3]);
      } else {
        float e = el[s] + ern[0];
        e = e > 0.f ? e : NSLOPE * e;
        float x = __expf(fminf(e, 80.f));
        sum[0] += x;
        if (i < EXCAP) exs[i] = x;
      }
    }
  }
  float inv[H];
  #pragma unroll
  for (int h = 0; h < H; ++h) {
    float v = sum[h];
    #pragma unroll
    for (int o = LPN / 2; o > 0; o >>= 1) v += __shfl_xor(v, o);
    inv[h] = v > 0.f ? 1.f / v : 0.f;
  }
  asm volatile("s_waitcnt lgkmcnt(0)" ::: "memory");
  const int degc = deg < EXCAP ? deg : EXCAP;
  int t = 0;
  if (H == 4) {
    float acc[8];
    #pragma unroll
    for (int k = 0; k < 8; ++k) acc[k] = 0.f;
    for (; t + 4 <= degc; t += 4) {
      int4 sa = *(const int4*)&esrc[off + t];
      int s[4] = {sa.x, sa.y, sa.z, sa.w};
      uint4 g[4];
      #pragma unroll
      for (int j = 0; j < 4; ++j)
        g[j] = *(const uint4*)&gp[(size_t)s[j] * 256 + sl * 8];
      #pragma unroll
      for (int j = 0; j < 4; ++j) {
        float4 x = *(const float4*)&exs[(t + j) * 4];
        acc[0] = fmaf(bflo(g[j].x), x.x, acc[0]);
        acc[1] = fmaf(bfhi(g[j].x), x.y, acc[1]);
        acc[2] = fmaf(bflo(g[j].y), x.z, acc[2]);
        acc[3] = fmaf(bfhi(g[j].y), x.w, acc[3]);
        acc[4] = fmaf(bflo(g[j].z), x.x, acc[4]);
        acc[5] = fmaf(bfhi(g[j].z), x.y, acc[5]);
        acc[6] = fmaf(bflo(g[j].w), x.z, acc[6]);
        acc[7] = fmaf(bfhi(g[j].w), x.w, acc[7]);
      }
    }
    for (; t < degc; ++t) {
      int s = esrc[off + t];
      uint4 g = *(const uint4*)&gp[(size_t)s * 256 + sl * 8];
      float4 x = *(const float4*)&exs[t * 4];
      acc[0] = fmaf(bflo(g.x), x.x, acc[0]);
      acc[1] = fmaf(bfhi(g.x), x.y, acc[1]);
      acc[2] = fmaf(bflo(g.y), x.z, acc[2]);
      acc[3] = fmaf(bfhi(g.y), x.w, acc[3]);
      acc[4] = fmaf(bflo(g.z), x.x, acc[4]);
      acc[5] = fmaf(bfhi(g.z), x.y, acc[5]);
      acc[6] = fmaf(bflo(g.w), x.z, acc[6]);
      acc[7] = fmaf(bfhi(g.w), x.w, acc[7]);
    }
    for (; t < deg; ++t) {
      int s = esrc[off + t];
      float4 L = *(const float4*)&el[s * 4];
      float lv[4] = {L.x, L.y, L.z, L.w};
      float xv[4];
      #pragma unroll
      for (int h = 0; h < 4; ++h) {
        float e = lv[h] + ern[h];
        e = e > 0.f ? e : NSLOPE * e;
        xv[h] = __expf(fminf(e, 80.f));
      }
      uint4 g = *(const uint4*)&gp[(size_t)s * 256 + sl * 8];
      acc[0] = fmaf(bflo(g.x), xv[0], acc[0]);
      acc[1] = fmaf(bfhi(g.x), xv[1], acc[1]);
      acc[2] = fmaf(bflo(g.y), xv[2], acc[2]);
      acc[3] = fmaf(bfhi(g.y), xv[3], acc[3]);
      acc[4] = fmaf(bflo(g.z), xv[0], acc[4]);
      acc[5] = fmaf(bfhi(g.z), xv[1], acc[5]);
      acc[6] = fmaf(bflo(g.w), xv[2], acc[6]);
      acc[7] = fmaf(bfhi(g.w), xv[3], acc[7]);
    }
    #pragma unroll
    for (int dd = 0; dd < 2; ++dd) {
      int d = 2 * sl + dd;
      #pragma unroll
      for (int hh = 0; hh < 4; ++hh) {
        float v = fmaf(acc[dd * 4 + hh], inv[hh], bias[hh * HID + d]);
        if (DO_ELU) v = v > 0.f ? v : expm1f(v);
        size_t oi = (size_t)n * 256 + hh * HID + d;
        if (SPLITOUT) {
          unsigned short hb = f2bf(v);
          outHi[oi] = hb;
          outLo[oi] = f2bf(v - bf2f(hb));
        } else {
          outF[oi] = v;
        }
      }
    }
  } else {
    float acc[4];
    #pragma unroll
    for (int k = 0; k < 4; ++k) acc[k] = 0.f;
    for (; t + 8 <= degc; t += 8) {
      int4 sa = *(const int4*)&esrc[off + t];
      int4 sb = *(const int4*)&esrc[off + t + 4];
      int s[8] = {sa.x, sa.y, sa.z, sa.w, sb.x, sb.y, sb.z, sb.w};
      uint2 g[8];
      #pragma unroll
      for (int j = 0; j < 8; ++j)
        g[j] = *(const uint2*)&gp[(size_t)s[j] * 64 + sl * 4];
      #pragma unroll
      for (int j = 0; j < 8; ++j) {
        float x = exs[t + j];
        acc[0] = fmaf(bflo(g[j].x), x, acc[0]);
        acc[1] = fmaf(bfhi(g[j].x), x, acc[1]);
        acc[2] = fmaf(bflo(g[j].y), x, acc[2]);
        acc[3] = fmaf(bfhi(g[j].y), x, acc[3]);
      }
    }
    for (; t < degc; ++t) {
      int s = esrc[off + t];
      uint2 g = *(const uint2*)&gp[(size_t)s * 64 + sl * 4];
      float x = exs[t];
      acc[0] = fmaf(bflo(g.x), x, acc[0]);
      acc[1] = fmaf(bfhi(g.x), x, acc[1]);
      acc[2] = fmaf(bflo(g.y), x, acc[2]);
      acc[3] = fmaf(bfhi(g.y), x, acc[3]);
    }
    for (; t < deg; ++t) {
      int s = esrc[off + t];
      float e = el[s] + ern[0];
      e = e > 0.f ? e : NSLOPE * e;
      float x = __expf(fminf(e, 80.f));
      uint2 g = *(const uint2*)&gp[(size_t)s * 64 + sl * 4];
      acc[0] = fmaf(bflo(g.x), x, acc[0]);
      acc[1] = fmaf(bfhi(g.x), x, acc[1]);
      acc[2] = fmaf(bflo(g.y), x, acc[2]);
      acc[3] = fmaf(bfhi(g.y), x, acc[3]);
    }
    #pragma unroll
    for (int k = 0; k < 4; ++k) {
      int d = 4 * sl + k;
      float v = fmaf(acc[k], inv[0], bias[d]);
      if (DO_ELU) v = v > 0.f ? v : expm1f(v);
      size_t oi = (size_t)n * HID + d;
      if (SPLITOUT) {
        unsigned short hb = f2bf(v);
        outHi[oi] = hb;
        outLo[oi] = f2bf(v - bf2f(hb));
      } else {
        outF[oi] = v;
      }
    }
  }
}

extern "C" void kernel_launch(void* const* d_in, const int* in_sizes, int n_in,
                              void* d_out, int out_size, void* d_ws, size_t ws_size,
                              hipStream_t stream) {
  const float* feat = (const float*)d_in[0];
  const int* src = (const int*)d_in[1];
  const int* dst = (const int*)d_in[2];
  const float* W1 = (const float*)d_in[3];
  const float* al1 = (const float*)d_in[4];
  const float* ar1 = (const float*)d_in[5];
  const float* b1 = (const float*)d_in[6];
  const float* W2 = (const float*)d_in[7];
  const float* al2 = (const float*)d_in[8];
  const float* ar2 = (const float*)d_in[9];
  const float* b2 = (const float*)d_in[10];
  const float* W3 = (const float*)d_in[11];
  const float* al3 = (const float*)d_in[12];
  const float* ar3 = (const float*)d_in[13];
  const float* b3 = (const float*)d_in[14];
  const int N = in_sizes[0] / 128;  // 50000 (< 65536 required for u32 edge packing)
  const int E = in_sizes[1];        // 800000

  char* w = (char*)d_ws;
  auto alloc = [&](size_t bytes) {
    void* p = (void*)w;
    w += (bytes + 255) & ~(size_t)255;
    return p;
  };
  unsigned short* pHi = (unsigned short*)alloc((size_t)N * 256 * 2);
  unsigned short* pLo = (unsigned short*)alloc((size_t)N * 256 * 2);
  float* Cbuf = (float*)alloc((size_t)N * 256 * 4);
  unsigned short* Gp = (unsigned short*)alloc((size_t)N * 256 * 2);
  float* el = (float*)alloc((size_t)N * 4 * 4);
  float* er = (float*)alloc((size_t)N * 4 * 4);
  int* deg = (int*)alloc((size_t)N * 4);
  int* cursor = (int*)alloc((size_t)N * 4);
  int* offs = (int*)alloc((size_t)(N + 1) * 4);
  int nb = (N + SB - 1) / SB;
  int* bsums = (int*)alloc((size_t)nb * 4);
  int* carry = (int*)alloc((size_t)nb * 4);
  int* esrc = (int*)alloc((size_t)E * 4);
  int nbk = (N + 255) >> 8;  // 196 buckets
  int* bcur = (int*)alloc((size_t)nbk * 4);
  unsigned* bbuf = (unsigned*)alloc((size_t)nbk * BCAP * 4);
  unsigned* ovf = (unsigned*)alloc((size_t)OVFCAP * 4);
  int* ovfcnt = (int*)alloc(256);
  unsigned short* W1h = (unsigned short*)alloc((size_t)256 * 128 * 2);
  unsigned short* W1l = (unsigned short*)alloc((size_t)256 * 128 * 2);
  unsigned short* W2h = (unsigned short*)alloc((size_t)256 * 256 * 2);
  unsigned short* W2l = (unsigned short*)alloc((size_t)256 * 256 * 2);
  unsigned short* W3h = (unsigned short*)alloc((size_t)64 * 256 * 2);
  unsigned short* W3l = (unsigned short*)alloc((size_t)64 * 256 * 2);

  // ---- CSR by dst (hierarchical binned fill) ----
  hipMemsetAsync(deg, 0, (size_t)N * 4, stream);
  hipMemsetAsync(bcur, 0, (size_t)nbk * 4, stream);
  hipMemsetAsync(ovfcnt, 0, 256, stream);
  int eb = (E + 255) / 256;
  k_count<<<eb, 256, 0, stream>>>(dst, deg, E);
  k_blocksums<<<nb, SB, 0, stream>>>(deg, bsums, N);
  k_scancarry<<<1, SB, 0, stream>>>(bsums, carry, nb);
  k_offsets<<<nb, SB, 0, stream>>>(deg, carry, offs, N, E);
  k_binA<<<256, 256, 0, stream>>>(src, dst, bcur, bbuf, ovf, ovfcnt, E, nbk);
  k_binB<<<nbk, 256, 0, stream>>>(bcur, bbuf, offs, cursor, esrc, N);
  k_ovf<<<1, 64, 0, stream>>>(ovf, ovfcnt, offs, cursor, esrc);

  // ---- weight transpose+split ----
  k_wsplit<<<(256 * 128 + 255) / 256, 256, 0, stream>>>(W1, W1h, W1l, 128, 256);
  k_wsplit<<<(256 * 256 + 255) / 256, 256, 0, stream>>>(W2, W2h, W2l, 256, 256);
  k_wsplit<<<(64 * 256 + 255) / 256, 256, 0, stream>>>(W3, W3h, W3l, 256, 64);

  // ---- feat split ----
  k_split<<<((N * 128) + 255) / 256, 256, 0, stream>>>(feat, pHi, pLo, N * 128);

  int rg = (N + 127) / 128;   // 391
  int ng4 = (N + 3) / 4;      // elr blocks
  int ag4 = (N + 1) / 2;      // agg<4>: 2 nodes/wave
  int ag1 = (N + 3) / 4;      // agg<1>: 4 nodes/wave
  // ---- layer 1 ----
  gemm_split<<<dim3(2, rg), 256, 0, stream>>>(pHi, pLo, W1h, W1l, Cbuf, Gp, N, 256, 128, 4);
  elr_kernel<<<ng4, 256, 0, stream>>>(Cbuf, al1, ar1, el, er, 4, N);
  agg_kernel<4, true, true><<<ag4, 64, 0, stream>>>(Gp, el, er, offs, esrc, b1, pHi, pLo, nullptr, N);
  // ---- layer 2 ----
  gemm_split<<<dim3(2, rg), 256, 0, stream>>>(pHi, pLo, W2h, W2l, Cbuf, Gp, N, 256, 256, 4);
  elr_kernel<<<ng4, 256, 0, stream>>>(Cbuf, al2, ar2, el, er, 4, N);
  agg_kernel<4, true, true><<<ag4, 64, 0, stream>>>(Gp, el, er, offs, esrc, b2, pHi, pLo, nullptr, N);
  // ---- layer 3 ----
  gemm_split<<<dim3(1, rg), 256, 0, stream>>>(pHi, pLo, W3h, W3l, Cbuf, Gp, N, 64, 256, 1);
  elr_kernel<<<ng4, 256, 0, stream>>>(Cbuf, al3, ar3, el, er, 1, N);
  agg_kernel<1, false, false><<<ag1, 64, 0, stream>>>(Gp, el, er, offs, esrc, b3, nullptr, nullptr, (float*)d_out, N);
}

// Round 14
// 437.772 us; speedup vs baseline: 2.0261x; 1.0129x over previous
//
#include <hip/hip_runtime.h>
#include <math.h>

#define HID 64
#define NSLOPE 0.2f
#define SB 512
#define EXCAP 256
#define BCAP 8192      // bucket capacity (mean 4096, +64 sigma)
#define OVFCAP 65536   // overflow list capacity (expected use: 0)
#define NBK_MAX 256    // max buckets (N < 65536)

typedef __attribute__((ext_vector_type(8))) short short8v;
typedef __attribute__((ext_vector_type(4))) float float4v;

__device__ inline unsigned short f2bf(float x) {
  unsigned u = __float_as_uint(x);
  u += 0x7fffu + ((u >> 16) & 1u);
  return (unsigned short)(u >> 16);
}
__device__ inline float bf2f(unsigned short h) {
  return __uint_as_float(((unsigned)h) << 16);
}
__device__ inline float bflo(unsigned u) { return __uint_as_float(u << 16); }
__device__ inline float bfhi(unsigned u) { return __uint_as_float(u & 0xffff0000u); }

// ---------------- split f32 -> (hi, lo) bf16 planes, elementwise ----------------
__global__ __launch_bounds__(256) void k_split(const float* __restrict__ x,
    unsigned short* __restrict__ hi, unsigned short* __restrict__ lo, int n) {
  int i = blockIdx.x * 256 + threadIdx.x;
  if (i < n) {
    float v = x[i];
    unsigned short h = f2bf(v);
    hi[i] = h;
    lo[i] = f2bf(v - bf2f(h));
  }
}

// ---------------- W [K,N] f32 -> Wt hi/lo [N,K] bf16 ----------------
__global__ __launch_bounds__(256) void k_wsplit(const float* __restrict__ W,
    unsigned short* __restrict__ Whi, unsigned short* __restrict__ Wlo, int K, int N) {
  int i = blockIdx.x * 256 + threadIdx.x;
  if (i < N * K) {
    int n = i / K, k = i - n * K;
    float v = W[(size_t)k * N + n];
    unsigned short h = f2bf(v);
    Whi[i] = h;
    Wlo[i] = f2bf(v - bf2f(h));
  }
}

// ---------------- Wal prep: Wal[k][j] = sum_d W[k][j*64+d]*al[j][d] (j<H: al, else ar)
__global__ __launch_bounds__(256) void k_walprep(const float* __restrict__ W,
    const float* __restrict__ al, const float* __restrict__ ar,
    float* __restrict__ Wal, int K, int Nc, int H) {
  int k = blockIdx.x * 256 + threadIdx.x;
  if (k >= K) return;
  for (int j = 0; j < H; ++j) {
    float sl = 0.f, sr = 0.f;
    for (int d = 0; d < HID; ++d) {
      float wv = W[(size_t)k * Nc + j * HID + d];
      sl = fmaf(wv, al[j * HID + d], sl);
      sr = fmaf(wv, ar[j * HID + d], sr);
    }
    Wal[(size_t)k * 2 * H + j] = sl;
    Wal[(size_t)k * 2 * H + H + j] = sr;
  }
}

// ---------------- el/er = x @ Wal, x = f32 feat [N][128] (layer 1) ----------------
__global__ __launch_bounds__(256) void k_elr_f32(const float* __restrict__ x,
    const float* __restrict__ Wal, float* __restrict__ el, float* __restrict__ er, int N) {
  int n = blockIdx.x * 4 + (threadIdx.x >> 6);
  int lane = threadIdx.x & 63;
  if (n >= N) return;
  float2 xv = *(const float2*)&x[(size_t)n * 128 + lane * 2];
  float p[8];
  #pragma unroll
  for (int j = 0; j < 8; ++j) p[j] = 0.f;
  #pragma unroll
  for (int kk = 0; kk < 2; ++kk) {
    float xk = (kk == 0) ? xv.x : xv.y;
    const float* wr = &Wal[(size_t)(lane * 2 + kk) * 8];
    float4 wa = *(const float4*)wr;
    float4 wb = *(const float4*)(wr + 4);
    p[0] = fmaf(xk, wa.x, p[0]); p[1] = fmaf(xk, wa.y, p[1]);
    p[2] = fmaf(xk, wa.z, p[2]); p[3] = fmaf(xk, wa.w, p[3]);
    p[4] = fmaf(xk, wb.x, p[4]); p[5] = fmaf(xk, wb.y, p[5]);
    p[6] = fmaf(xk, wb.z, p[6]); p[7] = fmaf(xk, wb.w, p[7]);
  }
  #pragma unroll
  for (int j = 0; j < 8; ++j)
    #pragma unroll
    for (int o = 32; o > 0; o >>= 1) p[j] += __shfl_xor(p[j], o);
  if (lane == 0) {
    *(float4*)&el[n * 4] = make_float4(p[0], p[1], p[2], p[3]);
    *(float4*)&er[n * 4] = make_float4(p[4], p[5], p[6], p[7]);
  }
}

// ---------------- el/er = x @ Wal, x = hi/lo bf16 planes [N][256] (layers 2,3) ----
template<int H>
__global__ __launch_bounds__(256) void k_elr_bf(const unsigned short* __restrict__ xhi,
    const unsigned short* __restrict__ xlo, const float* __restrict__ Wal,
    float* __restrict__ el, float* __restrict__ er, int N) {
  constexpr int NJ = 2 * H;
  int n = blockIdx.x * 4 + (threadIdx.x >> 6);
  int lane = threadIdx.x & 63;
  if (n >= N) return;
  uint2 hv = *(const uint2*)&xhi[(size_t)n * 256 + lane * 4];
  uint2 lv = *(const uint2*)&xlo[(size_t)n * 256 + lane * 4];
  float x[4] = { bflo(hv.x) + bflo(lv.x), bfhi(hv.x) + bfhi(lv.x),
                 bflo(hv.y) + bflo(lv.y), bfhi(hv.y) + bfhi(lv.y) };
  float p[NJ];
  #pragma unroll
  for (int j = 0; j < NJ; ++j) p[j] = 0.f;
  #pragma unroll
  for (int kk = 0; kk < 4; ++kk) {
    const float* wr = &Wal[(size_t)(lane * 4 + kk) * NJ];
    #pragma unroll
    for (int j = 0; j < NJ; ++j) p[j] = fmaf(x[kk], wr[j], p[j]);
  }
  #pragma unroll
  for (int j = 0; j < NJ; ++j)
    #pragma unroll
    for (int o = 32; o > 0; o >>= 1) p[j] += __shfl_xor(p[j], o);
  if (lane == 0) {
    #pragma unroll
    for (int j = 0; j < H; ++j) { el[n * H + j] = p[j]; er[n * H + j] = p[H + j]; }
  }
}

// ---------------- split-bf16 MFMA GEMM -> packed bf16 Gp only ----------------
__global__ __launch_bounds__(256) void gemm_split(
    const unsigned short* __restrict__ Ahi, const unsigned short* __restrict__ Alo,
    const unsigned short* __restrict__ Bhi, const unsigned short* __restrict__ Blo,
    unsigned short* __restrict__ Gp, int M, int Nc, int K, int H) {
  __shared__ __align__(16) unsigned short AsHi[128 * 40];
  __shared__ __align__(16) unsigned short AsLo[128 * 40];
  __shared__ __align__(16) unsigned short BsHi[128 * 40];
  __shared__ __align__(16) unsigned short BsLo[128 * 40];
  const int tid = threadIdx.x;
  const int lane = tid & 63, wid = tid >> 6;
  const int wr = wid >> 1, wc = wid & 1;
  const int row0 = blockIdx.y * 128;
  const int col0 = blockIdx.x * 128;
  float4v acc[4][4];
  #pragma unroll
  for (int mi = 0; mi < 4; ++mi)
    #pragma unroll
    for (int ni = 0; ni < 4; ++ni)
      acc[mi][ni] = (float4v){0.f, 0.f, 0.f, 0.f};

  const int sr = tid >> 2;
  const int sc8 = (tid & 3) * 8;
  const int lr = lane & 15, lk = (lane >> 4) * 8;

  for (int k0 = 0; k0 < K; k0 += 32) {
    #pragma unroll
    for (int half = 0; half < 2; ++half) {
      int row = sr + half * 64;
      int arow = row0 + row; if (arow > M - 1) arow = M - 1;
      int brow = col0 + row; if (brow > Nc - 1) brow = Nc - 1;
      *(short8v*)&AsHi[row * 40 + sc8] = *(const short8v*)&Ahi[(size_t)arow * K + k0 + sc8];
      *(short8v*)&AsLo[row * 40 + sc8] = *(const short8v*)&Alo[(size_t)arow * K + k0 + sc8];
      *(short8v*)&BsHi[row * 40 + sc8] = *(const short8v*)&Bhi[(size_t)brow * K + k0 + sc8];
      *(short8v*)&BsLo[row * 40 + sc8] = *(const short8v*)&Blo[(size_t)brow * K + k0 + sc8];
    }
    __syncthreads();
    short8v ah[4], alv[4], bh[4], bl[4];
    #pragma unroll
    for (int mi = 0; mi < 4; ++mi) {
      int r = wr * 64 + mi * 16 + lr;
      ah[mi]  = *(const short8v*)&AsHi[r * 40 + lk];
      alv[mi] = *(const short8v*)&AsLo[r * 40 + lk];
    }
    #pragma unroll
    for (int ni = 0; ni < 4; ++ni) {
      int r = wc * 64 + ni * 16 + lr;
      bh[ni] = *(const short8v*)&BsHi[r * 40 + lk];
      bl[ni] = *(const short8v*)&BsLo[r * 40 + lk];
    }
    #pragma unroll
    for (int mi = 0; mi < 4; ++mi)
      #pragma unroll
      for (int ni = 0; ni < 4; ++ni) {
        acc[mi][ni] = __builtin_amdgcn_mfma_f32_16x16x32_bf16(ah[mi], bh[ni], acc[mi][ni], 0, 0, 0);
        acc[mi][ni] = __builtin_amdgcn_mfma_f32_16x16x32_bf16(ah[mi], bl[ni], acc[mi][ni], 0, 0, 0);
        acc[mi][ni] = __builtin_amdgcn_mfma_f32_16x16x32_bf16(alv[mi], bh[ni], acc[mi][ni], 0, 0, 0);
      }
    __syncthreads();
  }
  #pragma unroll
  for (int mi = 0; mi < 4; ++mi) {
    int rbase = row0 + wr * 64 + mi * 16 + (lane >> 4) * 4;
    #pragma unroll
    for (int ni = 0; ni < 4; ++ni) {
      int cc = col0 + wc * 64 + ni * 16 + (lane & 15);
      if (cc < Nc) {
        int gcol = (cc & 63) * H + (cc >> 6);
        #pragma unroll
        for (int q = 0; q < 4; ++q) {
          int rr = rbase + q;
          if (rr < M) Gp[(size_t)rr * Nc + gcol] = f2bf(acc[mi][ni][q]);
        }
      }
    }
  }
}

// ---------------- CSR build (binned, no k_count) ----------------
__global__ __launch_bounds__(SB) void k_blocksums(const int* __restrict__ deg,
                                                  int* __restrict__ bsums, int n) {
  __shared__ int s[SB];
  int t = threadIdx.x, i = blockIdx.x * SB + t;
  s[t] = (i < n) ? deg[i] : 0;
  __syncthreads();
  for (int o = SB >> 1; o > 0; o >>= 1) { if (t < o) s[t] += s[t + o]; __syncthreads(); }
  if (t == 0) bsums[blockIdx.x] = s[0];
}
__global__ __launch_bounds__(SB) void k_scancarry(const int* __restrict__ bsums,
                                                   int* __restrict__ carry, int nb) {
  __shared__ int s[SB];
  int t = threadIdx.x;
  int v = (t < nb) ? bsums[t] : 0;
  s[t] = v; __syncthreads();
  for (int o = 1; o < SB; o <<= 1) {
    int u = (t >= o) ? s[t - o] : 0;
    __syncthreads(); s[t] += u; __syncthreads();
  }
  if (t < nb) carry[t] = s[t] - v;
}
__global__ __launch_bounds__(SB) void k_offsets(const int* __restrict__ deg,
    const int* __restrict__ carry, int* __restrict__ offs, int n, int E) {
  __shared__ int s[SB];
  int t = threadIdx.x, i = blockIdx.x * SB + t;
  int v = (i < n) ? deg[i] : 0;
  s[t] = v; __syncthreads();
  for (int o = 1; o < SB; o <<= 1) {
    int u = (t >= o) ? s[t - o] : 0;
    __syncthreads(); s[t] += u; __syncthreads();
  }
  if (i < n) offs[i] = carry[blockIdx.x] + s[t] - v;
  if (i == n) offs[n] = E;
}
// pass A: LDS-aggregated bucket reservation (1 global atomic per block*bucket).
__global__ __launch_bounds__(256) void k_binA(const int* __restrict__ src,
    const int* __restrict__ dst, int* __restrict__ bcur, unsigned* __restrict__ bbuf,
    unsigned* __restrict__ ovf, int* __restrict__ ovfcnt, int E, int nbk) {
  __shared__ int lcnt[NBK_MAX];
  __shared__ int lbase[NBK_MAX];
  const int tid = threadIdx.x;
  int per = (E + gridDim.x - 1) / gridDim.x;
  int e0 = blockIdx.x * per;
  int e1 = e0 + per; if (e1 > E) e1 = E;
  for (int b = tid; b < nbk; b += 256) lcnt[b] = 0;
  __syncthreads();
  for (int e = e0 + tid; e < e1; e += 256)
    atomicAdd(&lcnt[dst[e] >> 8], 1);
  __syncthreads();
  for (int b = tid; b < nbk; b += 256) {
    int c = lcnt[b];
    lbase[b] = (c > 0) ? atomicAdd(&bcur[b], c) : 0;
    lcnt[b] = 0;
  }
  __syncthreads();
  for (int e = e0 + tid; e < e1; e += 256) {
    int d = dst[e], s = src[e];
    int b = d >> 8;
    int pos = lbase[b] + atomicAdd(&lcnt[b], 1);
    unsigned packed = ((unsigned)d << 16) | (unsigned)s;
    if (pos < BCAP) {
      bbuf[(size_t)b * BCAP + pos] = packed;
    } else {
      int o = atomicAdd(ovfcnt, 1);
      if (o < OVFCAP) ovf[o] = packed;
    }
  }
}
// per-node degree from buckets (sequential bbuf read, LDS counters)
__global__ __launch_bounds__(256) void k_degB(const int* __restrict__ bcur,
    const unsigned* __restrict__ bbuf, int* __restrict__ deg, int N) {
  __shared__ int lcnt[256];
  int b = blockIdx.x;
  lcnt[threadIdx.x] = 0;
  __syncthreads();
  int cnt = bcur[b]; if (cnt > BCAP) cnt = BCAP;
  for (int i = threadIdx.x; i < cnt; i += 256)
    atomicAdd(&lcnt[(bbuf[(size_t)b * BCAP + i] >> 16) & 255], 1);
  __syncthreads();
  int n0 = b << 8;
  if (n0 + threadIdx.x < N) deg[n0 + threadIdx.x] = lcnt[threadIdx.x];
}
__global__ __launch_bounds__(64) void k_degovf(const unsigned* __restrict__ ovf,
    const int* __restrict__ ovfcnt, int* __restrict__ deg) {
  int cnt = *ovfcnt; if (cnt > OVFCAP) cnt = OVFCAP;
  for (int i = threadIdx.x; i < cnt; i += 64)
    atomicAdd(&deg[(int)(ovf[i] >> 16)], 1);
}
// pass B: one block per bucket; per-node cursors in LDS; export cursors for k_ovf.
__global__ __launch_bounds__(256) void k_binB(const int* __restrict__ bcur,
    const unsigned* __restrict__ bbuf, const int* __restrict__ offs,
    int* __restrict__ cursor, int* __restrict__ esrc, int N) {
  __shared__ int lcur[256];
  int b = blockIdx.x;
  int n0 = b << 8;
  int nn = N - n0; if (nn > 256) nn = 256;
  lcur[threadIdx.x] = 0;
  __syncthreads();
  int cnt = bcur[b]; if (cnt > BCAP) cnt = BCAP;
  for (int i = threadIdx.x; i < cnt; i += 256) {
    unsigned v = bbuf[(size_t)b * BCAP + i];
    int d = (int)(v >> 16), s = (int)(v & 0xffffu);
    int slot = offs[d] + atomicAdd(&lcur[d & 255], 1);
    esrc[slot] = s;
  }
  __syncthreads();
  if (threadIdx.x < nn) cursor[n0 + threadIdx.x] = lcur[threadIdx.x];
}
__global__ __launch_bounds__(64) void k_ovf(const unsigned* __restrict__ ovf,
    const int* __restrict__ ovfcnt, const int* __restrict__ offs,
    int* __restrict__ cursor, int* __restrict__ esrc) {
  int cnt = *ovfcnt; if (cnt > OVFCAP) cnt = OVFCAP;
  for (int i = threadIdx.x; i < cnt; i += 64) {
    unsigned v = ovf[i];
    int d = (int)(v >> 16), s = (int)(v & 0xffffu);
    int slot = offs[d] + atomicAdd(&cursor[d], 1);
    esrc[slot] = s;
  }
}

// ---- fused per-dst softmax + weighted gather-sum (r13 structure, unchanged) ----
template<int H, bool DO_ELU, bool SPLITOUT>
__global__ __launch_bounds__(64) void agg_kernel(const unsigned short* __restrict__ gp,
    const float* __restrict__ el, const float* __restrict__ er,
    const int* __restrict__ offs, const int* __restrict__ esrc,
    const float* __restrict__ bias,
    unsigned short* __restrict__ outHi, unsigned short* __restrict__ outLo,
    float* __restrict__ outF, int N) {
  constexpr int LPN = (H == 4) ? 32 : 16;
  constexpr int NPW = 64 / LPN;
  __shared__ __align__(16) float exs_all[NPW][EXCAP * H];
  const int lane = threadIdx.x;
  const int grp = lane / LPN;
  const int sl = lane % LPN;
  const int n = blockIdx.x * NPW + grp;
  if (n >= N) return;
  float* exs = exs_all[grp];
  const int off = offs[n];
  const int deg = offs[n + 1] - off;
  float ern[H];
  if (H == 4) {
    float4 R = *(const float4*)&er[n * 4];
    ern[0] = R.x; ern[1] = R.y; ern[2] = R.z; ern[3] = R.w;
  } else {
    ern[0] = er[n];
  }
  float sum[H];
  #pragma unroll
  for (int h = 0; h < H; ++h) sum[h] = 0.f;
  for (int base = 0; base < deg; base += LPN) {
    int i = base + sl;
    if (i < deg) {
      int s = esrc[off + i];
      if (H == 4) {
        float4 L = *(const float4*)&el[s * 4];
        float lv[4] = {L.x, L.y, L.z, L.w};
        float exv[4];
        #pragma unroll
        for (int h = 0; h < 4; ++h) {
          float e = lv[h] + ern[h];
          e = e > 0.f ? e : NSLOPE * e;
          exv[h] = __expf(fminf(e, 80.f));
          sum[h] += exv[h];
        }
        if (i < EXCAP)
          *(float4*)&exs[i * 4] = make_float4(exv[0], exv[1], exv[2], exv[3]);
      } else {
        float e = el[s] + ern[0];
        e = e > 0.f ? e : NSLOPE * e;
        float x = __expf(fminf(e, 80.f));
        sum[0] += x;
        if (i < EXCAP) exs[i] = x;
      }
    }
  }
  float inv[H];
  #pragma unroll
  for (int h = 0; h < H; ++h) {
    float v = sum[h];
    #pragma unroll
    for (int o = LPN / 2; o > 0; o >>= 1) v += __shfl_xor(v, o);
    inv[h] = v > 0.f ? 1.f / v : 0.f;
  }
  asm volatile("s_waitcnt lgkmcnt(0)" ::: "memory");
  const int degc = deg < EXCAP ? deg : EXCAP;
  int t = 0;
  if (H == 4) {
    float acc[8];
    #pragma unroll
    for (int k = 0; k < 8; ++k) acc[k] = 0.f;
    for (; t + 4 <= degc; t += 4) {
      int4 sa = *(const int4*)&esrc[off + t];
      int s[4] = {sa.x, sa.y, sa.z, sa.w};
      uint4 g[4];
      #pragma unroll
      for (int j = 0; j < 4; ++j)
        g[j] = *(const uint4*)&gp[(size_t)s[j] * 256 + sl * 8];
      #pragma unroll
      for (int j = 0; j < 4; ++j) {
        float4 x = *(const float4*)&exs[(t + j) * 4];
        acc[0] = fmaf(bflo(g[j].x), x.x, acc[0]);
        acc[1] = fmaf(bfhi(g[j].x), x.y, acc[1]);
        acc[2] = fmaf(bflo(g[j].y), x.z, acc[2]);
        acc[3] = fmaf(bfhi(g[j].y), x.w, acc[3]);
        acc[4] = fmaf(bflo(g[j].z), x.x, acc[4]);
        acc[5] = fmaf(bfhi(g[j].z), x.y, acc[5]);
        acc[6] = fmaf(bflo(g[j].w), x.z, acc[6]);
        acc[7] = fmaf(bfhi(g[j].w), x.w, acc[7]);
      }
    }
    for (; t < degc; ++t) {
      int s = esrc[off + t];
      uint4 g = *(const uint4*)&gp[(size_t)s * 256 + sl * 8];
      float4 x = *(const float4*)&exs[t * 4];
      acc[0] = fmaf(bflo(g.x), x.x, acc[0]);
      acc[1] = fmaf(bfhi(g.x), x.y, acc[1]);
      acc[2] = fmaf(bflo(g.y), x.z, acc[2]);
      acc[3] = fmaf(bfhi(g.y), x.w, acc[3]);
      acc[4] = fmaf(bflo(g.z), x.x, acc[4]);
      acc[5] = fmaf(bfhi(g.z), x.y, acc[5]);
      acc[6] = fmaf(bflo(g.w), x.z, acc[6]);
      acc[7] = fmaf(bfhi(g.w), x.w, acc[7]);
    }
    for (; t < deg; ++t) {
      int s = esrc[off + t];
      float4 L = *(const float4*)&el[s * 4];
      float lv[4] = {L.x, L.y, L.z, L.w};
      float xv[4];
      #pragma unroll
      for (int h = 0; h < 4; ++h) {
        float e = lv[h] + ern[h];
        e = e > 0.f ? e : NSLOPE * e;
        xv[h] = __expf(fminf(e, 80.f));
      }
      uint4 g = *(const uint4*)&gp[(size_t)s * 256 + sl * 8];
      acc[0] = fmaf(bflo(g.x), xv[0], acc[0]);
      acc[1] = fmaf(bfhi(g.x), xv[1], acc[1]);
      acc[2] = fmaf(bflo(g.y), xv[2], acc[2]);
      acc[3] = fmaf(bfhi(g.y), xv[3], acc[3]);
      acc[4] = fmaf(bflo(g.z), xv[0], acc[4]);
      acc[5] = fmaf(bfhi(g.z), xv[1], acc[5]);
      acc[6] = fmaf(bflo(g.w), xv[2], acc[6]);
      acc[7] = fmaf(bfhi(g.w), xv[3], acc[7]);
    }
    #pragma unroll
    for (int dd = 0; dd < 2; ++dd) {
      int d = 2 * sl + dd;
      #pragma unroll
      for (int hh = 0; hh < 4; ++hh) {
        float v = fmaf(acc[dd * 4 + hh], inv[hh], bias[hh * HID + d]);
        if (DO_ELU) v = v > 0.f ? v : expm1f(v);
        size_t oi = (size_t)n * 256 + hh * HID + d;
        if (SPLITOUT) {
          unsigned short hb = f2bf(v);
          outHi[oi] = hb;
          outLo[oi] = f2bf(v - bf2f(hb));
        } else {
          outF[oi] = v;
        }
      }
    }
  } else {
    float acc[4];
    #pragma unroll
    for (int k = 0; k < 4; ++k) acc[k] = 0.f;
    for (; t + 8 <= degc; t += 8) {
      int4 sa = *(const int4*)&esrc[off + t];
      int4 sb = *(const int4*)&esrc[off + t + 4];
      int s[8] = {sa.x, sa.y, sa.z, sa.w, sb.x, sb.y, sb.z, sb.w};
      uint2 g[8];
      #pragma unroll
      for (int j = 0; j < 8; ++j)
        g[j] = *(const uint2*)&gp[(size_t)s[j] * 64 + sl * 4];
      #pragma unroll
      for (int j = 0; j < 8; ++j) {
        float x = exs[t + j];
        acc[0] = fmaf(bflo(g[j].x), x, acc[0]);
        acc[1] = fmaf(bfhi(g[j].x), x, acc[1]);
        acc[2] = fmaf(bflo(g[j].y), x, acc[2]);
        acc[3] = fmaf(bfhi(g[j].y), x, acc[3]);
      }
    }
    for (; t < degc; ++t) {
      int s = esrc[off + t];
      uint2 g = *(const uint2*)&gp[(size_t)s * 64 + sl * 4];
      float x = exs[t];
      acc[0] = fmaf(bflo(g.x), x, acc[0]);
      acc[1] = fmaf(bfhi(g.x), x, acc[1]);
      acc[2] = fmaf(bflo(g.y), x, acc[2]);
      acc[3] = fmaf(bfhi(g.y), x, acc[3]);
    }
    for (; t < deg; ++t) {
      int s = esrc[off + t];
      float e = el[s] + ern[0];
      e = e > 0.f ? e : NSLOPE * e;
      float x = __expf(fminf(e, 80.f));
      uint2 g = *(const uint2*)&gp[(size_t)s * 64 + sl * 4];
      acc[0] = fmaf(bflo(g.x), x, acc[0]);
      acc[1] = fmaf(bfhi(g.x), x, acc[1]);
      acc[2] = fmaf(bflo(g.y), x, acc[2]);
      acc[3] = fmaf(bfhi(g.y), x, acc[3]);
    }
    #pragma unroll
    for (int k = 0; k < 4; ++k) {
      int d = 4 * sl + k;
      float v = fmaf(acc[k], inv[0], bias[d]);
      if (DO_ELU) v = v > 0.f ? v : expm1f(v);
      size_t oi = (size_t)n * HID + d;
      if (SPLITOUT) {
        unsigned short hb = f2bf(v);
        outHi[oi] = hb;
        outLo[oi] = f2bf(v - bf2f(hb));
      } else {
        outF[oi] = v;
      }
    }
  }
}

extern "C" void kernel_launch(void* const* d_in, const int* in_sizes, int n_in,
                              void* d_out, int out_size, void* d_ws, size_t ws_size,
                              hipStream_t stream) {
  const float* feat = (const float*)d_in[0];
  const int* src = (const int*)d_in[1];
  const int* dst = (const int*)d_in[2];
  const float* W1 = (const float*)d_in[3];
  const float* al1 = (const float*)d_in[4];
  const float* ar1 = (const float*)d_in[5];
  const float* b1 = (const float*)d_in[6];
  const float* W2 = (const float*)d_in[7];
  const float* al2 = (const float*)d_in[8];
  const float* ar2 = (const float*)d_in[9];
  const float* b2 = (const float*)d_in[10];
  const float* W3 = (const float*)d_in[11];
  const float* al3 = (const float*)d_in[12];
  const float* ar3 = (const float*)d_in[13];
  const float* b3 = (const float*)d_in[14];
  const int N = in_sizes[0] / 128;  // 50000 (< 65536 required for u32 edge packing)
  const int E = in_sizes[1];        // 800000

  char* w = (char*)d_ws;
  auto alloc = [&](size_t bytes) {
    void* p = (void*)w;
    w += (bytes + 255) & ~(size_t)255;
    return p;
  };
  unsigned short* pHi = (unsigned short*)alloc((size_t)N * 256 * 2);
  unsigned short* pLo = (unsigned short*)alloc((size_t)N * 256 * 2);
  unsigned short* Gp = (unsigned short*)alloc((size_t)N * 256 * 2);
  float* el = (float*)alloc((size_t)N * 4 * 4);
  float* er = (float*)alloc((size_t)N * 4 * 4);
  int* deg = (int*)alloc((size_t)N * 4);
  int* cursor = (int*)alloc((size_t)N * 4);
  int* offs = (int*)alloc((size_t)(N + 1) * 4);
  int nb = (N + SB - 1) / SB;
  int* bsums = (int*)alloc((size_t)nb * 4);
  int* carry = (int*)alloc((size_t)nb * 4);
  int* esrc = (int*)alloc((size_t)E * 4);
  int nbk = (N + 255) >> 8;  // 196 buckets
  int* bcur = (int*)alloc((size_t)nbk * 4);
  unsigned* bbuf = (unsigned*)alloc((size_t)nbk * BCAP * 4);
  unsigned* ovf = (unsigned*)alloc((size_t)OVFCAP * 4);
  int* ovfcnt = (int*)alloc(256);
  unsigned short* W1h = (unsigned short*)alloc((size_t)256 * 128 * 2);
  unsigned short* W1l = (unsigned short*)alloc((size_t)256 * 128 * 2);
  unsigned short* W2h = (unsigned short*)alloc((size_t)256 * 256 * 2);
  unsigned short* W2l = (unsigned short*)alloc((size_t)256 * 256 * 2);
  unsigned short* W3h = (unsigned short*)alloc((size_t)64 * 256 * 2);
  unsigned short* W3l = (unsigned short*)alloc((size_t)64 * 256 * 2);
  float* Wal1 = (float*)alloc((size_t)128 * 8 * 4);
  float* Wal2 = (float*)alloc((size_t)256 * 8 * 4);
  float* Wal3 = (float*)alloc((size_t)256 * 2 * 4);

  // ---- CSR by dst (binned fill; deg derived from bins, no k_count) ----
  hipMemsetAsync(bcur, 0, (size_t)nbk * 4, stream);
  hipMemsetAsync(ovfcnt, 0, 256, stream);
  k_binA<<<256, 256, 0, stream>>>(src, dst, bcur, bbuf, ovf, ovfcnt, E, nbk);
  k_degB<<<nbk, 256, 0, stream>>>(bcur, bbuf, deg, N);
  k_degovf<<<1, 64, 0, stream>>>(ovf, ovfcnt, deg);
  k_blocksums<<<nb, SB, 0, stream>>>(deg, bsums, N);
  k_scancarry<<<1, SB, 0, stream>>>(bsums, carry, nb);
  k_offsets<<<nb, SB, 0, stream>>>(deg, carry, offs, N, E);
  k_binB<<<nbk, 256, 0, stream>>>(bcur, bbuf, offs, cursor, esrc, N);
  k_ovf<<<1, 64, 0, stream>>>(ovf, ovfcnt, offs, cursor, esrc);

  // ---- weight transpose+split + Wal tables ----
  k_wsplit<<<(256 * 128 + 255) / 256, 256, 0, stream>>>(W1, W1h, W1l, 128, 256);
  k_wsplit<<<(256 * 256 + 255) / 256, 256, 0, stream>>>(W2, W2h, W2l, 256, 256);
  k_wsplit<<<(64 * 256 + 255) / 256, 256, 0, stream>>>(W3, W3h, W3l, 256, 64);
  k_walprep<<<1, 256, 0, stream>>>(W1, al1, ar1, Wal1, 128, 256, 4);
  k_walprep<<<1, 256, 0, stream>>>(W2, al2, ar2, Wal2, 256, 256, 4);
  k_walprep<<<1, 256, 0, stream>>>(W3, al3, ar3, Wal3, 256, 64, 1);

  // ---- feat split ----
  k_split<<<((N * 128) + 255) / 256, 256, 0, stream>>>(feat, pHi, pLo, N * 128);

  int rg = (N + 127) / 128;   // 391
  int ng4 = (N + 3) / 4;      // elr blocks
  int ag4 = (N + 1) / 2;      // agg<4>: 2 nodes/wave
  int ag1 = (N + 3) / 4;      // agg<1>: 4 nodes/wave
  // ---- layer 1 ----
  k_elr_f32<<<ng4, 256, 0, stream>>>(feat, Wal1, el, er, N);
  gemm_split<<<dim3(2, rg), 256, 0, stream>>>(pHi, pLo, W1h, W1l, Gp, N, 256, 128, 4);
  agg_kernel<4, true, true><<<ag4, 64, 0, stream>>>(Gp, el, er, offs, esrc, b1, pHi, pLo, nullptr, N);
  // ---- layer 2 ----
  k_elr_bf<4><<<ng4, 256, 0, stream>>>(pHi, pLo, Wal2, el, er, N);
  gemm_split<<<dim3(2, rg), 256, 0, stream>>>(pHi, pLo, W2h, W2l, Gp, N, 256, 256, 4);
  agg_kernel<4, true, true><<<ag4, 64, 0, stream>>>(Gp, el, er, offs, esrc, b2, pHi, pLo, nullptr, N);
  // ---- layer 3 ----
  k_elr_bf<1><<<ng4, 256, 0, stream>>>(pHi, pLo, Wal3, el, er, N);
  gemm_split<<<dim3(1, rg), 256, 0, stream>>>(pHi, pLo, W3h, W3l, Gp, N, 64, 256, 1);
  agg_kernel<1, false, false><<<ag1, 64, 0, stream>>>(Gp, el, er, offs, esrc, b3, nullptr, nullptr, (float*)d_out, N);
}